// Round 2
// baseline (450.741 us; speedup 1.0000x reference)
//
#include <hip/hip_runtime.h>

typedef unsigned short u16;
typedef __bf16 bf16x8 __attribute__((ext_vector_type(8)));
typedef float f32x4 __attribute__((ext_vector_type(4)));
typedef u16 u16x8 __attribute__((ext_vector_type(8)));

static constexpr int kNRoi = 2000;
static constexpr int kMPad = 2048;
static constexpr int kKin  = 12544;
static constexpr int kHid  = 1024;
static constexpr int kNOutPad = 512;
static constexpr int kNC = 81;
static constexpr int kND = 324;

// Measured facts (rounds 2-5 of prior session): inputs f32, outputs f32.
// b1/b2 skipped: train-mode BN mean-subtraction cancels them exactly.
// Round 1 (this session): LDS swizzle verified (bank conflicts 6.4M -> 0) but
// null on time -> 2-phase barrier-drain is the bottleneck (T2 regime gate).
// This round: 256x256/BK=64/8-wave restructure, 64 MFMA per barrier, raw
// s_barrier + asm vmcnt(0) on iteration-old loads (T3 minimum recipe).

__device__ __forceinline__ u16 f2bf(float f) {
  union { float f; unsigned u; } v; v.f = f;
  unsigned r = v.u + 0x7fffu + ((v.u >> 16) & 1u);   // RNE, finite inputs only
  return (u16)(r >> 16);
}

// ---- device transpose helpers (block-uniform branches call these) ----------
__device__ __forceinline__ void transpose64(const float* __restrict__ in,
                                            u16* __restrict__ out, int R, int C,
                                            int bx, int by, u16* t, int tid) {
  const int cb = bx * 64, rb = by * 64;
  const int rl = tid >> 4, cl = (tid & 15) * 4;
#pragma unroll
  for (int i = 0; i < 4; ++i) {
    int r = rl + i * 16;
    f32x4 v = *(const f32x4*)(in + (long)(rb + r) * C + cb + cl);
#pragma unroll
    for (int j = 0; j < 4; ++j) t[(cl + j) * 72 + r] = f2bf(v[j]);
  }
  __syncthreads();
  const int c2 = tid >> 3, r2 = (tid & 7) * 8;
#pragma unroll
  for (int i = 0; i < 2; ++i) {
    int c = c2 + i * 32;
    u16x8 v = *(const u16x8*)&t[c * 72 + r2];
    *(u16x8*)(out + (long)(cb + c) * R + rb + r2) = v;
  }
}

__device__ __forceinline__ void transpose32(const float* __restrict__ in,
                                            u16* __restrict__ out, int R, int C,
                                            int bx, int by, u16* t, int tid) {
  int tx = tid & 31, ty = tid >> 5;
  int cb = bx * 32, rb = by * 32;
#pragma unroll
  for (int i = 0; i < 4; ++i) {
    int r = rb + ty + i * 8, c = cb + tx;
    if (r < R && c < C) t[(ty + i * 8) * 33 + tx] = f2bf(in[(long)r * C + c]);
  }
  __syncthreads();
#pragma unroll
  for (int i = 0; i < 4; ++i) {
    int c = cb + ty + i * 8, r = rb + tx;
    if (c < C && r < R) out[(long)c * R + r] = t[tx * 33 + ty + i * 8];
  }
}

// ---- fused prep: A-convert + all weight transposes + zero-init -------------
__global__ __launch_bounds__(256) void prep(
    const float* __restrict__ pooled, const float* __restrict__ w1,
    const float* __restrict__ w2, const float* __restrict__ wl,
    const float* __restrict__ wd, u16* __restrict__ A1,
    u16* __restrict__ W1T, u16* __restrict__ W2T, u16* __restrict__ WHT,
    float* __restrict__ X1, float* __restrict__ S) {
  __shared__ u16 sh[64 * 72];
  const int tid = threadIdx.x;
  int id = blockIdx.x;
  if (id < 12250) {                       // pooled f32 -> A1 bf16 (25,088,000)
    long i = ((long)id * 256 + tid) * 8;
    f32x4 a = *(const f32x4*)(pooled + i);
    f32x4 b = *(const f32x4*)(pooled + i + 4);
    u16x8 h;
#pragma unroll
    for (int j = 0; j < 4; ++j) { h[j] = f2bf(a[j]); h[4 + j] = f2bf(b[j]); }
    *(u16x8*)(A1 + i) = h;
    return;
  }
  id -= 12250;
  if (id < 3136) { transpose64(w1, W1T, kKin, kHid, id & 15, id >> 4, sh, tid); return; }
  id -= 3136;
  if (id < 256)  { transpose64(w2, W2T, kHid, kHid, id & 15, id >> 4, sh, tid); return; }
  id -= 256;
  if (id < 96)   { transpose32(wl, WHT, kHid, kNC, id % 3, id / 3, sh, tid); return; }
  id -= 96;
  if (id < 352)  { transpose32(wd, WHT + kNC * kHid, kHid, kND, id % 11, id / 11, sh, tid); return; }
  id -= 352;
  if (id < 54) {                          // zero WHT rows 405..511 (pad)
    int idx = id * 256 + tid;
    if (idx < 13696) *(u16x8*)(WHT + 405 * kHid + idx * 8) = (u16x8){};
    return;
  }
  id -= 54;
  if (id < 2048) {                        // zero X1 (8,388,608 B)
    *(f32x4*)(X1 + ((long)id * 256 + tid) * 4) = (f32x4){};
    return;
  }
  id -= 2048;                             // zero S1/SS1/S2/SS2 (16,384 B)
  *(f32x4*)(S + ((long)id * 256 + tid) * 4) = (f32x4){};
}

// ---- 256x256 tile, BK=64, 8-wave split-K GEMM: C += A[M][K] * Bt[N][K]^T ---
// Grid: 8 * gy * gz blocks of 512. bx = bl&7 pins an M-panel (and all of its
// split-K atomic writers + A-panel sharers) to one XCD; by varies fastest so
// same-z blocks (sharing a 4MB A+B K-slice) run together in one L2.
// LDS: 2 x (A 256x64 + B 256x64) bf16 = 128 KiB -> 1 block/CU, 8 waves.
// Per iteration: issue all 8 stage loads at top, 4 quadrant-phases x 16 MFMA,
// then asm vmcnt(0) (loads are a full iteration old) + raw s_barrier.
// LDS XOR swizzle: 16B column-group cg stored at cg^(row&7); source is
// pre-swizzled per-lane, global_load_lds dest stays linear (rule 21).
__global__ __launch_bounds__(512, 2) void gemm256(
    const u16* __restrict__ A, const u16* __restrict__ Bt,
    float* __restrict__ C, int Mreal, int K, int N,
    int gy, int ntPer, int ntRem) {
  __shared__ u16 As[2][16384];
  __shared__ u16 Bs[2][16384];

  const int tid  = threadIdx.x;
  const int lane = tid & 63;
  const int w    = tid >> 6;
  const int wm   = (w >> 2) * 128;     // 2 M-wave-groups
  const int wn   = (w & 3) * 64;       // 4 N-wave-groups

  const int bl = blockIdx.x;
  const int bx = bl & 7;               // M-panel == XCD under round-robin
  const int sq = bl >> 3;
  const int by = sq % gy;
  const int z  = sq / gy;
  const int ktBase = z * ntPer + (z < ntRem ? z : ntRem);
  const int NT = ntPer + (z < ntRem ? 1 : 0);
  const long kb = (long)ktBase * 64;

  // ---- staging source pointers (per-lane, pre-swizzled column group) ----
  const int rA  = w * 8 + (lane >> 3);          // local row, j adds 64
  const int cgs = (lane & 7) ^ (rA & 7);        // swizzled 16B group
  const u16* ap[4];
  const u16* bp[4];
#pragma unroll
  for (int j = 0; j < 4; ++j) {
    int rloc = rA + j * 64;
    long arow = (long)bx * 256 + rloc; if (arow > Mreal - 1) arow = Mreal - 1;
    ap[j] = A + arow * K + kb + cgs * 8;
    long brow = (long)by * 256 + rloc;
    bp[j] = Bt + brow * K + kb + cgs * 8;
  }

#define STAGE(b) do {                                                          \
    _Pragma("unroll") for (int j_ = 0; j_ < 4; ++j_) {                         \
      __builtin_amdgcn_global_load_lds(                                        \
          (const __attribute__((address_space(1))) void*)ap[j_],               \
          (__attribute__((address_space(3))) void*)(&As[b][w * 512 + j_ * 4096]), 16, 0, 0); \
      __builtin_amdgcn_global_load_lds(                                        \
          (const __attribute__((address_space(1))) void*)bp[j_],               \
          (__attribute__((address_space(3))) void*)(&Bs[b][w * 512 + j_ * 4096]), 16, 0, 0); \
      ap[j_] += 64; bp[j_] += 64;                                              \
    }                                                                          \
  } while (0)

  // ---- fragment read geometry ----
  const int fr   = lane & 15;
  const int q    = lane >> 4;          // 16B k-slot within 32-k slice
  const int swzr = fr & 7;             // frag rows == fr (mod 8)

  f32x4 acc[8][4] = {};

#define LDA(mg) do { _Pragma("unroll")                                         \
    for (int i_ = 0; i_ < 4; ++i_) {                                           \
      const u16* p_ = as_ + (wm + (mg) * 64 + i_ * 16 + fr) * 64;              \
      af[i_][0] = *(const bf16x8*)(p_ + ((q ^ swzr) * 8));                     \
      af[i_][1] = *(const bf16x8*)(p_ + (((4 + q) ^ swzr) * 8));               \
    } } while (0)

#define LDB(dst, ng) do { _Pragma("unroll")                                    \
    for (int i_ = 0; i_ < 2; ++i_) {                                           \
      const u16* p_ = bs_ + (wn + (ng) * 32 + i_ * 16 + fr) * 64;              \
      dst[i_][0] = *(const bf16x8*)(p_ + ((q ^ swzr) * 8));                    \
      dst[i_][1] = *(const bf16x8*)(p_ + (((4 + q) ^ swzr) * 8));              \
    } } while (0)

#define QUAD(mg, ng, B_) do {                                                  \
    __builtin_amdgcn_s_setprio(1);                                             \
    _Pragma("unroll") for (int mi_ = 0; mi_ < 4; ++mi_)                        \
    _Pragma("unroll") for (int ni_ = 0; ni_ < 2; ++ni_)                        \
    _Pragma("unroll") for (int kk_ = 0; kk_ < 2; ++kk_)                        \
      acc[(mg) * 4 + mi_][(ng) * 2 + ni_] =                                    \
          __builtin_amdgcn_mfma_f32_16x16x32_bf16(                             \
              af[mi_][kk_], B_[ni_][kk_],                                      \
              acc[(mg) * 4 + mi_][(ng) * 2 + ni_], 0, 0, 0);                   \
    __builtin_amdgcn_s_setprio(0);                                             \
  } while (0)

  STAGE(0);
  asm volatile("s_waitcnt vmcnt(0)" ::: "memory");
  __builtin_amdgcn_s_barrier();
  __builtin_amdgcn_sched_barrier(0);

  int buf = 0;
  for (int t = 0; t < NT; ++t) {
    if (t + 1 < NT) STAGE(buf ^ 1);

    const u16* as_ = As[buf];
    const u16* bs_ = Bs[buf];
    bf16x8 af[4][2], bn0[2][2], bn1[2][2];

    LDA(0); LDB(bn0, 0);
    QUAD(0, 0, bn0);
    __builtin_amdgcn_sched_barrier(0);
    LDB(bn1, 1);
    QUAD(0, 1, bn1);
    __builtin_amdgcn_sched_barrier(0);
    LDA(1);
    QUAD(1, 1, bn1);
    __builtin_amdgcn_sched_barrier(0);
    QUAD(1, 0, bn0);

    if (t + 1 < NT) {
      asm volatile("s_waitcnt vmcnt(0)" ::: "memory");
      __builtin_amdgcn_s_barrier();
      __builtin_amdgcn_sched_barrier(0);
    }
    buf ^= 1;
  }
#undef STAGE
#undef LDA
#undef LDB
#undef QUAD

  const int row0 = bx * 256 + wm + q * 4;
  const int col0 = by * 256 + wn + fr;
#pragma unroll
  for (int mi = 0; mi < 8; ++mi)
#pragma unroll
    for (int ni = 0; ni < 4; ++ni)
#pragma unroll
      for (int e = 0; e < 4; ++e)
        atomicAdd(&C[(long)(row0 + mi * 16 + e) * N + col0 + ni * 16],
                  acc[mi][ni][e]);
}

// ---- colstats over first 2000 rows of X[.][1024] + optional zeroing --------
__global__ __launch_bounds__(256) void colstats_zero(
    const float* __restrict__ X, float* __restrict__ S, float* __restrict__ SS,
    float* __restrict__ Z) {
  int id = blockIdx.x;
  if (id < 320) {
    int c = (id & 3) * 256 + threadIdx.x;
    int r0 = (id >> 2) * 25;
    float s = 0.f, ss = 0.f;
    for (int r = r0; r < r0 + 25; ++r) {
      float v = X[(long)r * kHid + c];
      s += v; ss += v * v;
    }
    atomicAdd(&S[c], s);
    atomicAdd(&SS[c], ss);
  } else {
    id -= 320;
    *(f32x4*)(Z + ((long)id * 256 + threadIdx.x) * 4) = (f32x4){};
  }
}

// ---- BN(train) + ReLU + bf16 cast, finalize folded in ----------------------
__global__ __launch_bounds__(256) void bn_relu(
    const float* __restrict__ X, const float* __restrict__ S,
    const float* __restrict__ SS, const float* __restrict__ gamma,
    const float* __restrict__ beta, u16* __restrict__ H) {
  constexpr float invN = 1.f / (float)kNRoi;
  long i = ((long)blockIdx.x * 256 + threadIdx.x) * 8;
  int c = (int)(i & (kHid - 1));
  f32x4 x0 = *(const f32x4*)(X + i);
  f32x4 x1 = *(const f32x4*)(X + i + 4);
  f32x4 s0 = *(const f32x4*)(S + c),    s1 = *(const f32x4*)(S + c + 4);
  f32x4 q0 = *(const f32x4*)(SS + c),   q1 = *(const f32x4*)(SS + c + 4);
  f32x4 g0 = *(const f32x4*)(gamma + c), g1 = *(const f32x4*)(gamma + c + 4);
  f32x4 b0 = *(const f32x4*)(beta + c),  b1 = *(const f32x4*)(beta + c + 4);
  u16x8 h;
#pragma unroll
  for (int j = 0; j < 4; ++j) {
    float mu = s0[j] * invN;
    float var = q0[j] * invN - mu * mu;
    float sc = g0[j] * rsqrtf(var + 1e-3f);
    h[j] = f2bf(fmaxf(0.f, sc * x0[j] + (b0[j] - mu * sc)));
    mu = s1[j] * invN;
    var = q1[j] * invN - mu * mu;
    sc = g1[j] * rsqrtf(var + 1e-3f);
    h[4 + j] = f2bf(fmaxf(0.f, sc * x1[j] + (b1[j] - mu * sc)));
  }
  *(u16x8*)(H + i) = h;
}

// ---- bias + softmax + f32 outputs, one wave per row ------------------------
__global__ __launch_bounds__(256) void head_out(
    const float* __restrict__ X, const float* __restrict__ bl,
    const float* __restrict__ bd, float* __restrict__ out) {
  int lane = threadIdx.x & 63;
  int row = blockIdx.x * 4 + (threadIdx.x >> 6);
  if (row >= kNRoi) return;
  const float* xr = X + (long)row * kNOutPad;
  float v0 = xr[lane] + bl[lane];
  float v1 = (lane < kNC - 64) ? xr[64 + lane] + bl[64 + lane] : -3.0e38f;
  float m = fmaxf(v0, v1);
#pragma unroll
  for (int off = 32; off > 0; off >>= 1) m = fmaxf(m, __shfl_xor(m, off, 64));
  float e0 = __expf(v0 - m);
  float e1 = (lane < kNC - 64) ? __expf(v1 - m) : 0.f;
  float s = e0 + e1;
#pragma unroll
  for (int off = 32; off > 0; off >>= 1) s += __shfl_xor(s, off, 64);
  float inv = 1.f / s;
  float* lo = out + (long)row * kNC;
  float* pr = out + (long)kNRoi * kNC + (long)row * kNC;
  float* de = out + 2L * kNRoi * kNC + (long)row * kND;
  lo[lane] = v0;
  pr[lane] = e0 * inv;
  if (lane < kNC - 64) { lo[64 + lane] = v1; pr[64 + lane] = e1 * inv; }
#pragma unroll
  for (int j = 0; j < 5; ++j) {
    int c = lane + 64 * j;
    de[c] = xr[kNC + c] + bd[c];
  }
  if (lane < 4) { int c = lane + 320; de[c] = xr[kNC + c] + bd[c]; }
}

// ---- launch ----------------------------------------------------------------
extern "C" void kernel_launch(void* const* d_in, const int* in_sizes, int n_in,
                              void* d_out, int out_size, void* d_ws, size_t ws_size,
                              hipStream_t stream) {
  const float* pooled   = (const float*)d_in[0];
  const float* w1       = (const float*)d_in[1];
  const float* gamma1   = (const float*)d_in[3];
  const float* beta1    = (const float*)d_in[4];
  const float* w2       = (const float*)d_in[5];
  const float* gamma2   = (const float*)d_in[7];
  const float* beta2    = (const float*)d_in[8];
  const float* w_logits = (const float*)d_in[9];
  const float* b_logits = (const float*)d_in[10];
  const float* w_delta  = (const float*)d_in[11];
  const float* b_delta  = (const float*)d_in[12];

  char* ws = (char*)d_ws;
  u16*   W1T  = (u16*)(ws + 0);            // [1024][12544] bf16
  u16*   W2T  = (u16*)(ws + 25690112);     // [1024][1024]  bf16
  u16*   WHT  = (u16*)(ws + 27787264);     // [512][1024]   bf16 (rows 405..511 zero)
  float* X1   = (float*)(ws + 28835840);   // [2048][1024] f32
  u16*   H    = (u16*)(ws + 37224448);     // [2048][1024] bf16 (H1 then H2)
  float* S    = (float*)(ws + 41418752);   // S1|SS1|S2|SS2, 4x1024 f32
  u16*   A1   = (u16*)(ws + 41435136);     // [2000][12544] bf16 (dead after GEMM1)
  float* X2   = (float*)(ws + 41435136);   // [2048][1024] f32, overlaps dead A1
  float* XOUT = (float*)(ws + 49823744);   // [2048][512]  f32, overlaps dead A1

  float* S1  = S;
  float* SS1 = S + 1024;
  float* S2  = S + 2048;
  float* SS2 = S + 3072;

  // 1) fused prep: A-convert, weight transposes, zero X1/S/WHT-pad
  prep<<<18196, 256, 0, stream>>>(pooled, w1, w2, w_logits, w_delta,
                                  A1, W1T, W2T, WHT, X1, S);

  // 2) GEMM1: X1 += A1 @ W1T^T   (256^2 tiles, split-K 8: z<4 -> 25 K-tiles, else 24)
  gemm256<<<256, 512, 0, stream>>>(A1, W1T, X1, kNRoi, kKin, kHid, 4, 24, 4);

  // 3) BN1 stats + zero X2/XOUT (12,582,912 B -> 3072 zero-blocks)
  colstats_zero<<<320 + 3072, 256, 0, stream>>>(X1, S1, SS1, X2);
  bn_relu<<<(kMPad * kHid) / 2048, 256, 0, stream>>>(X1, S1, SS1, gamma1, beta1, H);

  // 4) GEMM2: X2 += H @ W2T^T   (split-K 8: 2 K-tiles per block)
  gemm256<<<256, 512, 0, stream>>>(H, W2T, X2, kMPad, kHid, kHid, 4, 2, 0);

  // 5) BN2 stats + apply
  colstats_zero<<<320, 256, 0, stream>>>(X2, S2, SS2, nullptr);
  bn_relu<<<(kMPad * kHid) / 2048, 256, 0, stream>>>(X2, S2, SS2, gamma2, beta2, H);

  // 6) GEMM3: XOUT += H @ WHT^T  (split-K 16: 1 K-tile per block)
  gemm256<<<256, 512, 0, stream>>>(H, WHT, XOUT, kMPad, kHid, kNOutPad, 2, 1, 0);

  // 7) bias + softmax + f32 outputs
  head_out<<<kNRoi / 4, 256, 0, stream>>>(XOUT, b_logits, b_delta, (float*)d_out);
}

// Round 4
// 440.934 us; speedup vs baseline: 1.0222x; 1.0222x over previous
//
#include <hip/hip_runtime.h>

typedef unsigned short u16;
typedef __bf16 bf16x8 __attribute__((ext_vector_type(8)));
typedef float f32x4 __attribute__((ext_vector_type(4)));
typedef u16 u16x8 __attribute__((ext_vector_type(8)));

static constexpr int kNRoi = 2000;
static constexpr int kMPad = 2048;
static constexpr int kKin  = 12544;
static constexpr int kHid  = 1024;
static constexpr int kNOutPad = 512;
static constexpr int kNC = 81;
static constexpr int kND = 324;

// Measured facts: inputs f32, outputs f32. b1/b2 skipped (BN mean cancels).
// R1: LDS swizzle verified (conflicts 6.4M->0), null on time (T2 regime gate).
// R2: 256^2/BK64 with vmcnt(0)-per-iter: MfmaUtil 20%; split-K atomics regressed.
// R3: crashed -- layout needed 125MB workspace; only 91.6MB is proven. Lesson:
//     never exceed an unmeasured harness limit.
// R4 (this): fold A-convert INTO GEMM1 (read pooled f32, reg-stage+cvt+swizzled
//     ds_write) -> A1 buffer deleted -> partials fit at its offset; all GEMMs
//     128x128/BK64/4-wave, 2 blocks/CU, counted vmcnt (never 0 in loop),
//     direct-store split-K partials (no atomics), fused reductions.
//     Workspace max 74,989,568 B < 91.6 MB proven.

__device__ __forceinline__ u16 f2bf(float f) {
  union { float f; unsigned u; } v; v.f = f;
  unsigned r = v.u + 0x7fffu + ((v.u >> 16) & 1u);   // RNE, finite inputs only
  return (u16)(r >> 16);
}

// ---- device transpose helpers (block-uniform branches call these) ----------
__device__ __forceinline__ void transpose64(const float* __restrict__ in,
                                            u16* __restrict__ out, int R, int C,
                                            int bx, int by, u16* t, int tid) {
  const int cb = bx * 64, rb = by * 64;
  const int rl = tid >> 4, cl = (tid & 15) * 4;
#pragma unroll
  for (int i = 0; i < 4; ++i) {
    int r = rl + i * 16;
    f32x4 v = *(const f32x4*)(in + (long)(rb + r) * C + cb + cl);
#pragma unroll
    for (int j = 0; j < 4; ++j) t[(cl + j) * 72 + r] = f2bf(v[j]);
  }
  __syncthreads();
  const int c2 = tid >> 3, r2 = (tid & 7) * 8;
#pragma unroll
  for (int i = 0; i < 2; ++i) {
    int c = c2 + i * 32;
    u16x8 v = *(const u16x8*)&t[c * 72 + r2];
    *(u16x8*)(out + (long)(cb + c) * R + rb + r2) = v;
  }
}

__device__ __forceinline__ void transpose32(const float* __restrict__ in,
                                            u16* __restrict__ out, int R, int C,
                                            int bx, int by, u16* t, int tid) {
  int tx = tid & 31, ty = tid >> 5;
  int cb = bx * 32, rb = by * 32;
#pragma unroll
  for (int i = 0; i < 4; ++i) {
    int r = rb + ty + i * 8, c = cb + tx;
    if (r < R && c < C) t[(ty + i * 8) * 33 + tx] = f2bf(in[(long)r * C + c]);
  }
  __syncthreads();
#pragma unroll
  for (int i = 0; i < 4; ++i) {
    int c = cb + ty + i * 8, r = rb + tx;
    if (c < C && r < R) out[(long)c * R + r] = t[tx * 33 + ty + i * 8];
  }
}

// ---- fused prep: weight transposes + zero-init (A-convert deleted) ---------
// grid = 3136 + 256 + 96 + 352 + 54 + 4 = 3898 blocks of 256
__global__ __launch_bounds__(256) void prep(
    const float* __restrict__ w1, const float* __restrict__ w2,
    const float* __restrict__ wl, const float* __restrict__ wd,
    u16* __restrict__ W1T, u16* __restrict__ W2T, u16* __restrict__ WHT,
    float* __restrict__ S) {
  __shared__ u16 sh[64 * 72];
  const int tid = threadIdx.x;
  int id = blockIdx.x;
  if (id < 3136) { transpose64(w1, W1T, kKin, kHid, id & 15, id >> 4, sh, tid); return; }
  id -= 3136;
  if (id < 256)  { transpose64(w2, W2T, kHid, kHid, id & 15, id >> 4, sh, tid); return; }
  id -= 256;
  if (id < 96)   { transpose32(wl, WHT, kHid, kNC, id % 3, id / 3, sh, tid); return; }
  id -= 96;
  if (id < 352)  { transpose32(wd, WHT + kNC * kHid, kHid, kND, id % 11, id / 11, sh, tid); return; }
  id -= 352;
  if (id < 54) {                          // zero WHT rows 405..511 (pad)
    int idx = id * 256 + tid;
    if (idx < 13696) *(u16x8*)(WHT + 405 * kHid + idx * 8) = (u16x8){};
    return;
  }
  id -= 54;                               // zero S1/SS1/S2/SS2 (16,384 B)
  *(f32x4*)(S + ((long)id * 256 + tid) * 4) = (f32x4){};
}

// ---- 128x128 tile, BK=64, 4-wave split-K GEMM, direct-store partials -------
// AF32=1: A operand is f32 (pooled), reg-staged + f2bf + swizzled ds_write.
// AF32=0: A operand is bf16, staged via global_load_lds like B.
// Cz[z] (stride zstride) = A[M][K-chunk] * Bt[N][K-chunk]^T. No atomics.
// Grid 512 blocks of 256 (2 blocks/CU, 64KB LDS each). Decode: xcd=bl&7 ->
// bx = xcd*2 + (s&1) (M-panel pinned to XCD for A-reuse in L2).
// Pipeline per K-tile t (counted vmcnt, never 0 in main loop):
//   issue stage(t+1); vmcnt(N) drains only tile-t loads (issued 1 iter ago);
//   barrier; 16 ds_read_b128 + 32 MFMA; [AF32: drain A-regs, cvt+ds_write];
//   barrier.
// LDS XOR-swizzle both sides (rule 21): 16B group g of row r lives at slot
// g^(r&7); gload_lds dest linear + source pre-swizzled; ds_write swizzled
// directly; reads XOR the same term. Verified conflict-free in R1.
template<int AF32>
__global__ __launch_bounds__(256, 2) void gemm128(
    const float* __restrict__ Af, const u16* __restrict__ Ah,
    const u16* __restrict__ Bt, float* __restrict__ Cz, long zstride,
    int Mreal, int K, int N, int gy, int ntPer) {
  __shared__ u16 As[2][8192];
  __shared__ u16 Bs[2][8192];
  const int tid  = threadIdx.x;
  const int lane = tid & 63;
  const int w    = tid >> 6;
  const int wm   = (w >> 1) * 64;
  const int wn   = (w & 1) * 64;

  const int bl  = blockIdx.x;
  const int s   = bl >> 3;
  const int bx  = (bl & 7) * 2 + (s & 1);
  const int t2  = s >> 1;
  const int by  = t2 % gy;
  const int z   = t2 / gy;
  const long kb = (long)z * ntPer * 64;
  const int NT  = ntPer;

  // staging geometry: dest byte o = j*4096 + w*1024 + lane*16
  //   -> row = j*32 + w*8 + (lane>>3), group = lane&7
  //   -> source group = (lane&7) ^ (row&7) = (lane&7) ^ ((lane>>3)&7)
  const int rS = w * 8 + (lane >> 3);
  const int sg = (lane & 7) ^ ((lane >> 3) & 7);
  const u16* bp[4];
#pragma unroll
  for (int j = 0; j < 4; ++j)
    bp[j] = Bt + (long)(by * 128 + rS + j * 32) * K + kb + sg * 8;

  const u16* ap[4];
  const float* afp = nullptr;
  int rw = 0, hw = 0;
  if (AF32) {
    rw = tid >> 1; hw = tid & 1;                  // row, half (32 f32 each)
    long arow = (long)bx * 128 + rw; if (arow > Mreal - 1) arow = Mreal - 1;
    afp = Af + arow * K + kb + hw * 32;
  } else {
#pragma unroll
    for (int j = 0; j < 4; ++j) {
      long arow = (long)bx * 128 + rS + j * 32; if (arow > Mreal - 1) arow = Mreal - 1;
      ap[j] = Ah + arow * K + kb + sg * 8;
    }
  }

#define GLDS(p, dst) __builtin_amdgcn_global_load_lds( \
    (const __attribute__((address_space(1))) void*)(p), \
    (__attribute__((address_space(3))) void*)(dst), 16, 0, 0)
#define STG_B(b) do { _Pragma("unroll") for (int j_ = 0; j_ < 4; ++j_) { \
    GLDS(bp[j_], &Bs[b][j_ * 2048 + w * 512]); bp[j_] += 64; } } while (0)
#define STG_A(b) do { _Pragma("unroll") for (int j_ = 0; j_ < 4; ++j_) { \
    GLDS(ap[j_], &As[b][j_ * 2048 + w * 512]); ap[j_] += 64; } } while (0)

  f32x4 ar[8];
#define LDA32 do { _Pragma("unroll") for (int j_ = 0; j_ < 8; ++j_) \
    ar[j_] = *(const f32x4*)(afp + j_ * 4); afp += 64; } while (0)
  // write A half-row: groups 4h..4h+3 (source cols 32h+8k..) at swizzled slots
#define WRA(b) do { _Pragma("unroll") for (int k_ = 0; k_ < 4; ++k_) { \
    u16x8 hh; _Pragma("unroll") for (int e_ = 0; e_ < 4; ++e_) { \
      hh[e_] = f2bf(ar[2 * k_][e_]); hh[4 + e_] = f2bf(ar[2 * k_ + 1][e_]); } \
    *(u16x8*)(&As[b][rw * 64 + ((hw * 4 + k_) ^ (rw & 7)) * 8]) = hh; } } while (0)

  const int fr = lane & 15;
  const int q  = lane >> 4;
  const int g0 = (q ^ (fr & 7)) * 8;        // kk0 16B-group (swizzled)
  const int g1 = ((q + 4) ^ (fr & 7)) * 8;  // kk1

  f32x4 acc[4][4] = {};

#define LDFRAG(dst, base, off, gg) do { _Pragma("unroll") for (int i_ = 0; i_ < 4; ++i_) \
    dst[i_] = *(const bf16x8*)((base) + ((off) + i_ * 16 + fr) * 64 + (gg)); } while (0)
#define MM16(aa, bb) do { __builtin_amdgcn_s_setprio(1); \
    _Pragma("unroll") for (int mi_ = 0; mi_ < 4; ++mi_) \
    _Pragma("unroll") for (int ni_ = 0; ni_ < 4; ++ni_) \
      acc[mi_][ni_] = __builtin_amdgcn_mfma_f32_16x16x32_bf16( \
          aa[mi_], bb[ni_], acc[mi_][ni_], 0, 0, 0); \
    __builtin_amdgcn_s_setprio(0); } while (0)

  // ---- prologue: tile 0 ----
  if (AF32) {
    LDA32;                                  // 8 vm
    STG_B(0);                               // +4 -> 12
    asm volatile("s_waitcnt vmcnt(4)" ::: "memory");   // A-regs landed
    WRA(0);
  } else {
    STG_A(0); STG_B(0);                     // 8 vm
  }

  int cur = 0;
  for (int t = 0; t < NT; ++t) {
    const int nb = cur ^ 1;
    const bool more = (t + 1 < NT);
    if (more) {
      if (AF32) { LDA32; } else { STG_A(nb); }
      STG_B(nb);
      if (AF32) asm volatile("s_waitcnt vmcnt(12)" ::: "memory"); // drain B(t)
      else      asm volatile("s_waitcnt vmcnt(8)"  ::: "memory"); // drain A(t)+B(t)
    } else {
      asm volatile("s_waitcnt vmcnt(0)" ::: "memory");
    }
    __builtin_amdgcn_s_barrier();           // tile t visible to all waves
    __builtin_amdgcn_sched_barrier(0);

    const u16* as_ = As[cur];
    const u16* bs_ = Bs[cur];
    bf16x8 a0[4], b0[4], a1[4], b1[4];
    LDFRAG(a0, as_, wm, g0); LDFRAG(b0, bs_, wn, g0);
    MM16(a0, b0);
    LDFRAG(a1, as_, wm, g1); LDFRAG(b1, bs_, wn, g1);
    MM16(a1, b1);

    if (more && AF32) {
      asm volatile("s_waitcnt vmcnt(4)" ::: "memory");  // A-regs(t+1) landed
      WRA(nb);
      asm volatile("s_waitcnt lgkmcnt(0)" ::: "memory"); // ds_writes visible
    }
    __builtin_amdgcn_s_barrier();           // all done reading cur
    cur = nb;
  }
#undef GLDS
#undef STG_A
#undef STG_B
#undef LDA32
#undef WRA
#undef LDFRAG
#undef MM16

  float* Cw = Cz + (long)z * zstride;
  const int row0 = bx * 128 + wm + q * 4;
  const int col0 = by * 128 + wn + fr;
#pragma unroll
  for (int mi = 0; mi < 4; ++mi)
#pragma unroll
    for (int ni = 0; ni < 4; ++ni)
#pragma unroll
      for (int e = 0; e < 4; ++e)
        Cw[(long)(row0 + mi * 16 + e) * N + col0 + ni * 16] = acc[mi][ni][e];
}

// ---- sum split-K partials -> X, fused BN column stats over rows<2000 -------
// grid 256: col-group = id&3 (256 cols), row-group = id>>2 (32 rows each).
__global__ __launch_bounds__(256) void reduce_stats(
    const float* __restrict__ Cz, float* __restrict__ X,
    float* __restrict__ S, float* __restrict__ SS, int nz) {
  const int col = (blockIdx.x & 3) * 256 + threadIdx.x;
  const int r0 = (blockIdx.x >> 2) * 32;
  float s = 0.f, ss = 0.f;
  for (int r = r0; r < r0 + 32; ++r) {
    float x = 0.f;
    for (int zz = 0; zz < nz; ++zz)
      x += Cz[((long)zz * kMPad + r) * kHid + col];
    X[(long)r * kHid + col] = x;
    if (r < kNRoi) { s += x; ss += x * x; }
  }
  atomicAdd(&S[col], s);
  atomicAdd(&SS[col], ss);
}

// ---- BN(train) + ReLU + bf16 cast, finalize folded in ----------------------
__global__ __launch_bounds__(256) void bn_relu(
    const float* __restrict__ X, const float* __restrict__ S,
    const float* __restrict__ SS, const float* __restrict__ gamma,
    const float* __restrict__ beta, u16* __restrict__ H) {
  constexpr float invN = 1.f / (float)kNRoi;
  long i = ((long)blockIdx.x * 256 + threadIdx.x) * 8;
  int c = (int)(i & (kHid - 1));
  f32x4 x0 = *(const f32x4*)(X + i);
  f32x4 x1 = *(const f32x4*)(X + i + 4);
  f32x4 s0 = *(const f32x4*)(S + c),    s1 = *(const f32x4*)(S + c + 4);
  f32x4 q0 = *(const f32x4*)(SS + c),   q1 = *(const f32x4*)(SS + c + 4);
  f32x4 g0 = *(const f32x4*)(gamma + c), g1 = *(const f32x4*)(gamma + c + 4);
  f32x4 b0 = *(const f32x4*)(beta + c),  b1 = *(const f32x4*)(beta + c + 4);
  u16x8 h;
#pragma unroll
  for (int j = 0; j < 4; ++j) {
    float mu = s0[j] * invN;
    float var = q0[j] * invN - mu * mu;
    float sc = g0[j] * rsqrtf(var + 1e-3f);
    h[j] = f2bf(fmaxf(0.f, sc * x0[j] + (b0[j] - mu * sc)));
    mu = s1[j] * invN;
    var = q1[j] * invN - mu * mu;
    sc = g1[j] * rsqrtf(var + 1e-3f);
    h[4 + j] = f2bf(fmaxf(0.f, sc * x1[j] + (b1[j] - mu * sc)));
  }
  *(u16x8*)(H + i) = h;
}

// ---- sum 8 GEMM3 partials + bias + softmax + f32 outputs, 1 wave/row -------
__device__ __forceinline__ float rd8(const float* __restrict__ xr, int c) {
  float v = 0.f;
#pragma unroll
  for (int z = 0; z < 8; ++z) v += xr[(long)z * kMPad * kNOutPad + c];
  return v;
}

__global__ __launch_bounds__(256) void head_out(
    const float* __restrict__ Xz, const float* __restrict__ bl,
    const float* __restrict__ bd, float* __restrict__ out) {
  int lane = threadIdx.x & 63;
  int row = blockIdx.x * 4 + (threadIdx.x >> 6);
  if (row >= kNRoi) return;
  const float* xr = Xz + (long)row * kNOutPad;
  float v0 = rd8(xr, lane) + bl[lane];
  float v1 = (lane < kNC - 64) ? rd8(xr, 64 + lane) + bl[64 + lane] : -3.0e38f;
  float m = fmaxf(v0, v1);
#pragma unroll
  for (int off = 32; off > 0; off >>= 1) m = fmaxf(m, __shfl_xor(m, off, 64));
  float e0 = __expf(v0 - m);
  float e1 = (lane < kNC - 64) ? __expf(v1 - m) : 0.f;
  float s = e0 + e1;
#pragma unroll
  for (int off = 32; off > 0; off >>= 1) s += __shfl_xor(s, off, 64);
  float inv = 1.f / s;
  float* lo = out + (long)row * kNC;
  float* pr = out + (long)kNRoi * kNC + (long)row * kNC;
  float* de = out + 2L * kNRoi * kNC + (long)row * kND;
  lo[lane] = v0;
  pr[lane] = e0 * inv;
  if (lane < kNC - 64) { lo[64 + lane] = v1; pr[64 + lane] = e1 * inv; }
#pragma unroll
  for (int j = 0; j < 5; ++j) {
    int c = lane + 64 * j;
    de[c] = rd8(xr, kNC + c) + bd[c];
  }
  if (lane < 4) { int c = lane + 320; de[c] = rd8(xr, kNC + c) + bd[c]; }
}

// ---- launch ----------------------------------------------------------------
extern "C" void kernel_launch(void* const* d_in, const int* in_sizes, int n_in,
                              void* d_out, int out_size, void* d_ws, size_t ws_size,
                              hipStream_t stream) {
  const float* pooled   = (const float*)d_in[0];
  const float* w1       = (const float*)d_in[1];
  const float* gamma1   = (const float*)d_in[3];
  const float* beta1    = (const float*)d_in[4];
  const float* w2       = (const float*)d_in[5];
  const float* gamma2   = (const float*)d_in[7];
  const float* beta2    = (const float*)d_in[8];
  const float* w_logits = (const float*)d_in[9];
  const float* b_logits = (const float*)d_in[10];
  const float* w_delta  = (const float*)d_in[11];
  const float* b_delta  = (const float*)d_in[12];

  char* ws = (char*)d_ws;
  // Layout (bytes), max end = 74,989,568 < 91,611,136 proven-safe:
  u16*   W1T = (u16*)(ws + 0);            // [1024][12544] bf16  25,690,112
  u16*   W2T = (u16*)(ws + 25690112);     // [1024][1024]  bf16   2,097,152
  u16*   WHT = (u16*)(ws + 27787264);     // [512][1024]   bf16   1,048,576
  float* S   = (float*)(ws + 28835840);   // S1|SS1|S2|SS2        16,384
  u16*   H   = (u16*)(ws + 28852224);     // [2048][1024]  bf16   4,194,304
  float* X   = (float*)(ws + 33046528);   // [2048][1024]  f32    8,388,608
  float* Pz  = (float*)(ws + 41435136);   // partials, up to 33,554,432

  float* S1  = S;
  float* SS1 = S + 1024;
  float* S2  = S + 2048;
  float* SS2 = S + 3072;

  // 1) prep: weight transposes + zero S/WHT-pad (A-convert deleted)
  prep<<<3898, 256, 0, stream>>>(w1, w2, w_logits, w_delta, W1T, W2T, WHT, S);

  // 2) GEMM1: Pz[z] = pooled(f32) @ W1T^T, split-K 4, NT=49, 512 blocks
  gemm128<1><<<512, 256, 0, stream>>>(pooled, nullptr, W1T, Pz, 2048L * 1024,
                                      kNRoi, kKin, kHid, 8, 49);

  // 3) reduce partials -> X + BN1 stats; BN1+ReLU -> H
  reduce_stats<<<256, 256, 0, stream>>>(Pz, X, S1, SS1, 4);
  bn_relu<<<(kMPad * kHid) / 2048, 256, 0, stream>>>(X, S1, SS1, gamma1, beta1, H);

  // 4) GEMM2: Pz[z] = H @ W2T^T, split-K 4, NT=4, 512 blocks
  gemm128<0><<<512, 256, 0, stream>>>(nullptr, H, W2T, Pz, 2048L * 1024,
                                      kMPad, kHid, kHid, 8, 4);

  // 5) reduce -> X + BN2 stats; BN2+ReLU -> H
  reduce_stats<<<256, 256, 0, stream>>>(Pz, X, S2, SS2, 4);
  bn_relu<<<(kMPad * kHid) / 2048, 256, 0, stream>>>(X, S2, SS2, gamma2, beta2, H);

  // 6) GEMM3: Pz[z] = H @ WHT^T, split-K 8, NT=2, 512 blocks
  gemm128<0><<<512, 256, 0, stream>>>(nullptr, H, WHT, Pz, 2048L * 512,
                                      kMPad, kHid, kNOutPad, 4, 2);

  // 7) sum 8 partials + bias + softmax + f32 outputs
  head_out<<<kNRoi / 4, 256, 0, stream>>>(Pz, b_logits, b_delta, (float*)d_out);
}